// Round 1
// baseline (361.127 us; speedup 1.0000x reference)
//
#include <hip/hip_runtime.h>
#include <hip/hip_bf16.h>

// Problem constants
constexpr int B = 4, C = 64, H = 192, W = 192;
constexpr int HEADS = 4, D = 16;           // d = C/HEADS
constexpr int BLK = 8, HALO = 3, WIN = 14; // WIN = BLK + 2*HALO
constexpr int NH = H / BLK, NW = W / BLK;  // 24 x 24 blocks
constexpr int HW = H * W;                  // 36864
constexpr int O = 3 * C;                   // 192 qkv channels
constexpr int KST = 20;                    // LDS row stride (floats) for k/v/o tiles

// ---------------------------------------------------------------------------
// Kernel 1: qkv = w_qkv @ x per pixel (1x1 conv). q channels pre-scaled by
// d^-0.5 = 0.25. Output stored bf16 in workspace, layout (B, O, H, W).
// Each thread owns one pixel; its 64 input channels live in VGPRs; the w row
// is loaded with a wave-uniform address (compiler should emit s_load).
// ---------------------------------------------------------------------------
__global__ __launch_bounds__(256) void qkv_kernel(
    const float* __restrict__ x, const float* __restrict__ w,
    __hip_bfloat16* __restrict__ qkv) {
  const int pix = blockIdx.x * 256 + threadIdx.x;   // grid covers B*H*W exactly
  const int b = pix / HW;
  const int hw = pix - b * HW;

  const float* xp = x + (size_t)b * C * HW + hw;
  float xr[C];
#pragma unroll
  for (int c = 0; c < C; ++c) xr[c] = xp[(size_t)c * HW];

  __hip_bfloat16* qp = qkv + (size_t)b * O * HW + hw;
  for (int o = 0; o < O; ++o) {
    const float4* wr = reinterpret_cast<const float4*>(w + o * C); // uniform addr
    float acc = 0.f;
#pragma unroll
    for (int c4 = 0; c4 < C / 4; ++c4) {
      float4 wv = wr[c4];
      acc = fmaf(wv.x, xr[4 * c4 + 0], acc);
      acc = fmaf(wv.y, xr[4 * c4 + 1], acc);
      acc = fmaf(wv.z, xr[4 * c4 + 2], acc);
      acc = fmaf(wv.w, xr[4 * c4 + 3], acc);
    }
    if (o < C) acc *= 0.25f;  // q scale, d^-0.5 = 16^-0.5 = 1/4 exactly
    qp[(size_t)o * HW] = __float2bfloat16(acc);
  }
}

// ---------------------------------------------------------------------------
// Kernel 2: one workgroup per (window, head). 256 threads.
//   thread t: query row r = t>>2 (0..63), key quarter qi = t&3 (49 keys each).
// k is staged into LDS with rel_h/rel_w added (zero-padded OOB positions also
// get rel, matching the reference's pad-then-add order); v staged plain.
// ---------------------------------------------------------------------------
__global__ __launch_bounds__(256) void attn_kernel(
    const __hip_bfloat16* __restrict__ qkv,
    const float* __restrict__ rel_h, const float* __restrict__ rel_w,
    float* __restrict__ out) {
  __shared__ __align__(16) float k_lds[WIN * WIN * KST];
  __shared__ __align__(16) float v_lds[WIN * WIN * KST];
  __shared__ __align__(16) float o_lds[BLK * BLK * KST];

  const int tid = threadIdx.x;
  const int head = blockIdx.x & 3;
  const int win = blockIdx.x >> 2;
  const int b = win / (NH * NW);
  const int wrem = win - b * (NH * NW);
  const int bh = wrem / NW;
  const int bw = wrem - bh * NW;
  const int y0 = bh * BLK - HALO;
  const int x0 = bw * BLK - HALO;

  // ---- stage k (+rel) and v into LDS, coalesced over wx ----
  const __hip_bfloat16* kbase = qkv + ((size_t)b * O + C + head * D) * HW;
  const __hip_bfloat16* vbase = qkv + ((size_t)b * O + 2 * C + head * D) * HW;
  for (int i = tid; i < WIN * WIN * D; i += 256) {
    const int wx = i % WIN;
    const int t2 = i / WIN;
    const int wy = t2 % WIN;
    const int c = t2 / WIN;
    const int y = y0 + wy;
    const int xx = x0 + wx;
    const bool inb = (y >= 0) & (y < H) & (xx >= 0) & (xx < W);
    const size_t goff = (size_t)c * HW + y * W + xx;
    float kv = inb ? __bfloat162float(kbase[goff]) : 0.f;
    float vv = inb ? __bfloat162float(vbase[goff]) : 0.f;
    const float rel = (c < D / 2) ? rel_h[wy * (D / 2) + c]
                                  : rel_w[wx * (D / 2) + (c - D / 2)];
    const int j = wy * WIN + wx;
    k_lds[j * KST + c] = kv + rel;
    v_lds[j * KST + c] = vv;
  }

  // ---- load this thread's q row (already scaled by 0.25 in kernel 1) ----
  const int r = tid >> 2, qi = tid & 3;
  const int py = r >> 3, px = r & 7;
  float qreg[D];
  const __hip_bfloat16* qbase = qkv + ((size_t)b * O + head * D) * HW +
                                (bh * BLK + py) * W + bw * BLK + px;
#pragma unroll
  for (int c = 0; c < D; ++c) qreg[c] = __bfloat162float(qbase[(size_t)c * HW]);

  __syncthreads();

  // ---- sim = q . k for this thread's 49 keys ----
  float s[49];
  float m = -1e30f;
#pragma unroll
  for (int jj = 0; jj < 49; ++jj) {
    const float4* kr =
        reinterpret_cast<const float4*>(&k_lds[(qi * 49 + jj) * KST]);
    float acc = 0.f;
#pragma unroll
    for (int c4 = 0; c4 < 4; ++c4) {
      float4 kv = kr[c4];
      acc = fmaf(qreg[4 * c4 + 0], kv.x, acc);
      acc = fmaf(qreg[4 * c4 + 1], kv.y, acc);
      acc = fmaf(qreg[4 * c4 + 2], kv.z, acc);
      acc = fmaf(qreg[4 * c4 + 3], kv.w, acc);
    }
    s[jj] = acc;
    m = fmaxf(m, acc);
  }

  // ---- softmax across the 4 lanes sharing a row (adjacent lanes) ----
  m = fmaxf(m, __shfl_xor(m, 1));
  m = fmaxf(m, __shfl_xor(m, 2));
  float sum = 0.f;
#pragma unroll
  for (int jj = 0; jj < 49; ++jj) {
    s[jj] = __expf(s[jj] - m);
    sum += s[jj];
  }
  sum += __shfl_xor(sum, 1);
  sum += __shfl_xor(sum, 2);
  const float inv = 1.f / sum;

  // ---- out = p . v ----
  float o[D] = {};
#pragma unroll
  for (int jj = 0; jj < 49; ++jj) {
    const float4* vr =
        reinterpret_cast<const float4*>(&v_lds[(qi * 49 + jj) * KST]);
    const float p = s[jj];
#pragma unroll
    for (int c4 = 0; c4 < 4; ++c4) {
      float4 vv = vr[c4];
      o[4 * c4 + 0] = fmaf(p, vv.x, o[4 * c4 + 0]);
      o[4 * c4 + 1] = fmaf(p, vv.y, o[4 * c4 + 1]);
      o[4 * c4 + 2] = fmaf(p, vv.z, o[4 * c4 + 2]);
      o[4 * c4 + 3] = fmaf(p, vv.w, o[4 * c4 + 3]);
    }
  }
#pragma unroll
  for (int c = 0; c < D; ++c) {
    o[c] += __shfl_xor(o[c], 1);
    o[c] += __shfl_xor(o[c], 2);
  }

  if (qi == 0) {
#pragma unroll
    for (int c4 = 0; c4 < 4; ++c4) {
      float4 t;
      t.x = o[4 * c4 + 0] * inv;
      t.y = o[4 * c4 + 1] * inv;
      t.z = o[4 * c4 + 2] * inv;
      t.w = o[4 * c4 + 3] * inv;
      reinterpret_cast<float4*>(&o_lds[r * KST])[c4] = t;
    }
  }
  __syncthreads();

  // ---- write out, channel-major, coalesced over px ----
  for (int i = tid; i < BLK * BLK * D; i += 256) {
    const int c = i >> 6;
    const int p = i & 63;
    const int ppy = p >> 3, ppx = p & 7;
    out[((size_t)b * C + head * D + c) * HW + (bh * BLK + ppy) * W + bw * BLK +
        ppx] = o_lds[p * KST + c];
  }
}

extern "C" void kernel_launch(void* const* d_in, const int* in_sizes, int n_in,
                              void* d_out, int out_size, void* d_ws,
                              size_t ws_size, hipStream_t stream) {
  const float* x = (const float*)d_in[0];      // (4, 64, 192, 192)
  const float* w_qkv = (const float*)d_in[1];  // (192, 64)
  const float* rel_h = (const float*)d_in[2];  // (1, 14, 1, 8)
  const float* rel_w = (const float*)d_in[3];  // (1, 1, 14, 8)
  float* out = (float*)d_out;                  // (4, 64, 192, 192)

  __hip_bfloat16* qkv = (__hip_bfloat16*)d_ws;  // (4, 192, 192, 192) bf16

  qkv_kernel<<<(B * HW) / 256, 256, 0, stream>>>(x, w_qkv, qkv);
  attn_kernel<<<B * NH * NW * HEADS, 256, 0, stream>>>(qkv, rel_h, rel_w, out);
}

// Round 2
// 305.405 us; speedup vs baseline: 1.1825x; 1.1825x over previous
//
#include <hip/hip_runtime.h>
#include <hip/hip_bf16.h>

// Problem constants
constexpr int B = 4, C = 64, H = 192, W = 192;
constexpr int HEADS = 4, D = 16;           // d = C/HEADS
constexpr int BLK = 8, HALO = 3, WIN = 14; // WIN = BLK + 2*HALO
constexpr int NH = H / BLK, NW = W / BLK;  // 24 x 24 windows
constexpr int HW = H * W;                  // 36864
constexpr int O = 3 * C;                   // 192 qkv channels

typedef __attribute__((ext_vector_type(8))) short short8v;
typedef __attribute__((ext_vector_type(8))) __bf16 bf16x8;
typedef __attribute__((ext_vector_type(4))) float f32x4;

#define MFMA_BUILTIN 1

__device__ inline f32x4 mfma_bf16(short8v a, short8v b, f32x4 c) {
#if MFMA_BUILTIN
  return __builtin_amdgcn_mfma_f32_16x16x32_bf16(
      __builtin_bit_cast(bf16x8, a), __builtin_bit_cast(bf16x8, b), c, 0, 0, 0);
#else
  asm("v_mfma_f32_16x16x32_bf16 %0, %1, %2, %0" : "+v"(c) : "v"(a), "v"(b));
  return c;
#endif
}

__device__ inline float bf2f(unsigned short u) {
  union { unsigned int i; float f; } v;
  v.i = ((unsigned int)u) << 16;
  return v.f;
}
__device__ inline unsigned short f2bf(float f) {
  __bf16 h = (__bf16)f;
  return __builtin_bit_cast(unsigned short, h);
}

// ---------------------------------------------------------------------------
// Kernel 1: qkv projection, output layout (B, H, W, O) bf16 (pixel-major).
// blockIdx.y = section (0=q,1=k,2=v): 3x parallelism, each section's w slice
// is 16 KB (L1-resident). q pre-scaled by d^-0.5 = 0.25.
// ---------------------------------------------------------------------------
__global__ __launch_bounds__(256) void qkv_kernel(
    const float* __restrict__ x, const float* __restrict__ w,
    unsigned short* __restrict__ qkv) {
  const int pix = blockIdx.x * 256 + threadIdx.x;
  const int sec = blockIdx.y;
  const int b = pix / HW;
  const int hw = pix - b * HW;

  const float* xp = x + (size_t)b * C * HW + hw;
  float xr[C];
#pragma unroll
  for (int c = 0; c < C; ++c) xr[c] = xp[(size_t)c * HW];

  const float scale = (sec == 0) ? 0.25f : 1.0f;
  unsigned short* qp = qkv + (size_t)pix * O + sec * C;
  const float* wbase = w + sec * C * C;

  for (int og = 0; og < C / 4; ++og) {
    float a4[4];
#pragma unroll
    for (int oo = 0; oo < 4; ++oo) {
      const float4* wr = reinterpret_cast<const float4*>(wbase + (og * 4 + oo) * C);
      float acc = 0.f;
#pragma unroll
      for (int c4 = 0; c4 < C / 4; ++c4) {
        float4 wv = wr[c4];
        acc = fmaf(wv.x, xr[4 * c4 + 0], acc);
        acc = fmaf(wv.y, xr[4 * c4 + 1], acc);
        acc = fmaf(wv.z, xr[4 * c4 + 2], acc);
        acc = fmaf(wv.w, xr[4 * c4 + 3], acc);
      }
      a4[oo] = acc * scale;
    }
    ushort4 st;
    st.x = f2bf(a4[0]);
    st.y = f2bf(a4[1]);
    st.z = f2bf(a4[2]);
    st.w = f2bf(a4[3]);
    *reinterpret_cast<ushort4*>(qp + og * 4) = st;
  }
}

// ---------------------------------------------------------------------------
// Kernel 2: MFMA window attention. One block (256 thr = 4 waves) per window;
// wave = head. sim^T = mfma(K_tile, Q^T) so the D-layout feeds PV's B operand
// in-register; PV: O^T = mfma(V^T_frag, P^T) over 32-key tiles. V^T columns
// are stored in the PV slot permutation. d padded 16->32 by zeroing h>=2
// fragment halves. Keys padded 196->208(K)/224(V) with finite junk; their p
// is forced to 0 (tile 12, h>=1) so they contribute nothing.
// ---------------------------------------------------------------------------
__global__ __launch_bounds__(256) void attn_kernel(
    const unsigned short* __restrict__ qkv,
    const float* __restrict__ rel_h, const float* __restrict__ rel_w,
    float* __restrict__ out) {
  __shared__ unsigned short k_lds[4][208 * 16];  // [head][key][d]
  __shared__ unsigned short v_lds[4][16 * 224];  // [head][d][key-slot perm]

  const int tid = threadIdx.x;
  const int win = blockIdx.x;
  const int b = win / (NH * NW);
  const int wrem = win - b * (NH * NW);
  const int bh = wrem / NW;
  const int bw = wrem - bh * NW;
  const int y0 = bh * BLK - HALO;
  const int x0 = bw * BLK - HALO;

  // ---- stage K (+rel, ->bf16) rows and V^T (permuted cols) for all heads ---
  for (int i = tid; i < 224 * 16; i += 256) {   // 14 iters exactly
    const int pixel = i >> 4;                   // 0..223 (196..223 virtual)
    const int g = i & 15;                       // 8 k-chunks, 8 v-chunks
    const int wy = pixel / WIN;                 // 0..15
    const int wx = pixel - wy * WIN;
    const int y = y0 + wy, xx = x0 + wx;
    const bool inb = (y >= 0) & (y < H) & (xx >= 0) & (xx < W);
    uint4 raw = make_uint4(0u, 0u, 0u, 0u);
    if (inb)
      raw = *reinterpret_cast<const uint4*>(
          qkv + ((size_t)(b * HW + y * W + xx)) * O + C + g * 8);
    const unsigned short* us = reinterpret_cast<const unsigned short*>(&raw);
    const int head = (g & 7) >> 1;
    const int c0 = (g & 1) * 8;
    if (g < 8) {  // K: unpack, +rel, repack bf16
      const int wyc = (wy < WIN) ? wy : (WIN - 1);  // clamp for virtual rows
      const float* relp = (g & 1) ? (rel_w + wx * 8) : (rel_h + wyc * 8);
      const float4 r0 = *reinterpret_cast<const float4*>(relp);
      const float4 r1 = *reinterpret_cast<const float4*>(relp + 4);
      float rl[8] = {r0.x, r0.y, r0.z, r0.w, r1.x, r1.y, r1.z, r1.w};
      unsigned short res[8];
#pragma unroll
      for (int e = 0; e < 8; ++e) res[e] = f2bf(bf2f(us[e]) + rl[e]);
      if (pixel < 208) {
        uint4 packed;
        unsigned int* pw = reinterpret_cast<unsigned int*>(&packed);
#pragma unroll
        for (int e = 0; e < 4; ++e)
          pw[e] = (unsigned int)res[2 * e] | ((unsigned int)res[2 * e + 1] << 16);
        *reinterpret_cast<uint4*>(&k_lds[head][pixel * 16 + c0]) = packed;
      }
    } else {  // V: transposed store into PV slot order
      const int r32 = pixel & 31;
      const int j = (((r32 >> 2) & 3) << 3) | ((r32 >> 4) << 2) | (r32 & 3);
      const int col = (pixel & ~31) | j;
#pragma unroll
      for (int e = 0; e < 8; ++e) v_lds[head][(c0 + e) * 224 + col] = us[e];
    }
  }
  __syncthreads();

  const int lane = tid & 63;
  const int head = tid >> 6;
  const int r = lane & 15;   // qrow offset / V^T channel
  const int hq = lane >> 4;  // 16-lane group
  const unsigned short* kbase = k_lds[head];
  const unsigned short* vbase = v_lds[head];
  const short8v z8 = {0, 0, 0, 0, 0, 0, 0, 0};

  for (int qs = 0; qs < 4; ++qs) {
    const int qrow = qs * 16 + r;
    const int y = bh * BLK + (qrow >> 3);
    const int xx = bw * BLK + (qrow & 7);

    // Q^T fragment direct from global: Q[qrow][8h..8h+7], h>=2 -> zero pad
    short8v qf = *reinterpret_cast<const short8v*>(
        qkv + ((size_t)(b * HW + y * W + xx)) * O + head * D + (hq & 1) * 8);
    qf = (hq < 2) ? qf : z8;

    // sim^T tiles: D col=lane&15=qrow, row=4*hq+reg=key-in-tile
    f32x4 sim[13];
#pragma unroll
    for (int t = 0; t < 13; ++t) {
      short8v kf = *reinterpret_cast<const short8v*>(
          kbase + (16 * t + r) * 16 + (hq & 1) * 8);
      kf = (hq < 2) ? kf : z8;
      f32x4 z4 = {0.f, 0.f, 0.f, 0.f};
      sim[t] = mfma_bf16(kf, qf, z4);
    }

    // softmax over keys (regs x tiles, then lanes ^16, ^32)
    float m = -1e30f;
#pragma unroll
    for (int t = 0; t < 13; ++t)
#pragma unroll
      for (int e = 0; e < 4; ++e) m = fmaxf(m, sim[t][e]);
    m = fmaxf(m, __shfl_xor(m, 16));
    m = fmaxf(m, __shfl_xor(m, 32));
    float sum = 0.f;
#pragma unroll
    for (int t = 0; t < 13; ++t) {
#pragma unroll
      for (int e = 0; e < 4; ++e) {
        float p = __expf(sim[t][e] - m);
        if (t == 12 && hq >= 1) p = 0.f;  // key >= 196: pad
        sim[t][e] = p;
        sum += p;
      }
    }
    sum += __shfl_xor(sum, 16);
    sum += __shfl_xor(sum, 32);
    const float inv = 1.f / sum;

    // PV: O^T = sum_tau mfma(V^T frag, P^T frag)
    f32x4 oacc = {0.f, 0.f, 0.f, 0.f};
#pragma unroll
    for (int tau = 0; tau < 7; ++tau) {
      short8v pf;
#pragma unroll
      for (int e = 0; e < 4; ++e) pf[e] = (short)f2bf(sim[2 * tau][e]);
#pragma unroll
      for (int e = 0; e < 4; ++e)
        pf[4 + e] = (2 * tau + 1 < 13) ? (short)f2bf(sim[2 * tau + 1][e]) : (short)0;
      short8v vf = *reinterpret_cast<const short8v*>(
          vbase + r * 224 + 32 * tau + 8 * hq);
      oacc = mfma_bf16(vf, pf, oacc);
    }

    // epilogue: lane holds O^T[c=4*hq+e][qrow]; scale by 1/sum
    float* op = out + ((size_t)b * C + head * D + 4 * hq) * HW + y * W + xx;
#pragma unroll
    for (int e = 0; e < 4; ++e) op[(size_t)e * HW] = oacc[e] * inv;
  }
}

extern "C" void kernel_launch(void* const* d_in, const int* in_sizes, int n_in,
                              void* d_out, int out_size, void* d_ws,
                              size_t ws_size, hipStream_t stream) {
  const float* x = (const float*)d_in[0];      // (4, 64, 192, 192)
  const float* w_qkv = (const float*)d_in[1];  // (192, 64)
  const float* rel_h = (const float*)d_in[2];  // (1, 14, 1, 8)
  const float* rel_w = (const float*)d_in[3];  // (1, 1, 14, 8)
  float* out = (float*)d_out;                  // (4, 64, 192, 192)

  unsigned short* qkv = (unsigned short*)d_ws;  // (B, H, W, O) bf16

  dim3 g1(B * HW / 256, 3);
  qkv_kernel<<<g1, 256, 0, stream>>>(x, w_qkv, qkv);
  attn_kernel<<<B * NH * NW, 256, 0, stream>>>(qkv, rel_h, rel_w, out);
}

// Round 3
// 118.506 us; speedup vs baseline: 3.0473x; 2.5771x over previous
//
#include <hip/hip_runtime.h>
#include <hip/hip_bf16.h>

// Problem constants
constexpr int B = 4, C = 64, H = 192, W = 192;
constexpr int HEADS = 4, D = 16;           // d = C/HEADS
constexpr int BLK = 8, HALO = 3, WIN = 14; // WIN = BLK + 2*HALO
constexpr int NH = H / BLK, NW = W / BLK;  // 24 x 24 windows
constexpr int HW = H * W;                  // 36864
constexpr int O = 3 * C;                   // 192 qkv channels

typedef __attribute__((ext_vector_type(8))) short short8v;
typedef __attribute__((ext_vector_type(8))) __bf16 bf16x8;
typedef __attribute__((ext_vector_type(4))) float f32x4;

__device__ inline f32x4 mfma_bf16(short8v a, short8v b, f32x4 c) {
  return __builtin_amdgcn_mfma_f32_16x16x32_bf16(
      __builtin_bit_cast(bf16x8, a), __builtin_bit_cast(bf16x8, b), c, 0, 0, 0);
}

__device__ inline float bf2f(unsigned short u) {
  union { unsigned int i; float f; } v;
  v.i = ((unsigned int)u) << 16;
  return v.f;
}
__device__ inline unsigned short f2bf(float f) {
  __bf16 h = (__bf16)f;
  return __builtin_bit_cast(unsigned short, h);
}

// ---------------------------------------------------------------------------
// Kernel 1: qkv projection as MFMA GEMM, computing D^T = W (o x c) * X^T
// (c x pix) per 16x16 tile. Output (B,H,W,O) bf16 pixel-major; each lane
// stores 4 consecutive o as one ushort4 (lines merge in L2 across o-tiles).
// w staged in LDS bf16 with XOR chunk swizzle (conflict-free ds_read_b128);
// x fragments read direct from global (4 full 64B lines per load instr).
// q rows (o<64) pre-scaled by d^-0.5 = 0.25.
// ---------------------------------------------------------------------------
__global__ __launch_bounds__(256) void qkv_mfma(
    const float* __restrict__ x, const float* __restrict__ w,
    unsigned short* __restrict__ qkv) {
  __shared__ unsigned short wlds[192 * 64];
  const int tid = threadIdx.x;

  // ---- cooperative w stage: fp32 -> bf16, 8-ch chunks XOR-swizzled by o&7 --
  const float4* wf4 = reinterpret_cast<const float4*>(w);
#pragma unroll
  for (int it = 0; it < 12; ++it) {
    const int idx = it * 256 + tid;  // 3072 float4s
    const int o = idx >> 4;
    const int c = (idx & 15) << 2;
    const float4 wv = wf4[idx];
    ushort4 st;
    st.x = f2bf(wv.x);
    st.y = f2bf(wv.y);
    st.z = f2bf(wv.z);
    st.w = f2bf(wv.w);
    const int sw = (((c >> 3) ^ (o & 7)) << 3) + (c & 4);
    *reinterpret_cast<ushort4*>(&wlds[o * 64 + sw]) = st;
  }

  // ---- load this wave's X^T fragments direct from global ----
  const int wave = tid >> 6, lane = tid & 63;
  const int p = lane & 15, g = lane >> 4;
  const int pix_w = blockIdx.x * 128 + wave * 32;  // 32 pixels per wave
  const int b = pix_w / HW;                        // tiles never cross b
  const int hw = pix_w - b * HW + p;
  const float* xb = x + (size_t)b * C * HW;

  short8v xf[2][2];  // [pixtile][kstep]
#pragma unroll
  for (int pt = 0; pt < 2; ++pt) {
#pragma unroll
    for (int ks = 0; ks < 2; ++ks) {
      unsigned short u[8];
#pragma unroll
      for (int j = 0; j < 8; ++j)
        u[j] = f2bf(xb[(size_t)(ks * 32 + g * 8 + j) * HW + hw + pt * 16]);
      unsigned int pw[4];
#pragma unroll
      for (int e = 0; e < 4; ++e)
        pw[e] = (unsigned int)u[2 * e] | ((unsigned int)u[2 * e + 1] << 16);
      xf[pt][ks] = __builtin_bit_cast(short8v, *reinterpret_cast<uint4*>(pw));
    }
  }
  __syncthreads();

  // ---- 12 o-tiles x 2 pix-tiles, K=64 via 2 chained mfma ----
#pragma unroll
  for (int ot = 0; ot < 12; ++ot) {
    short8v af[2];
#pragma unroll
    for (int ks = 0; ks < 2; ++ks)
      af[ks] = *reinterpret_cast<const short8v*>(
          wlds + (ot * 16 + p) * 64 + (((((ks << 2) | g)) ^ (p & 7)) << 3));
    const float s = (ot < 4) ? 0.25f : 1.0f;  // q scale
#pragma unroll
    for (int pt = 0; pt < 2; ++pt) {
      f32x4 acc = {0.f, 0.f, 0.f, 0.f};
      acc = mfma_bf16(af[0], xf[pt][0], acc);
      acc = mfma_bf16(af[1], xf[pt][1], acc);
      ushort4 st;
      st.x = f2bf(acc[0] * s);
      st.y = f2bf(acc[1] * s);
      st.z = f2bf(acc[2] * s);
      st.w = f2bf(acc[3] * s);
      *reinterpret_cast<ushort4*>(
          qkv + (size_t)(pix_w + pt * 16 + p) * O + ot * 16 + g * 4) = st;
    }
  }
}

// ---------------------------------------------------------------------------
// Kernel 2: MFMA window attention (unchanged from R2 — verified).
// ---------------------------------------------------------------------------
__global__ __launch_bounds__(256) void attn_kernel(
    const unsigned short* __restrict__ qkv,
    const float* __restrict__ rel_h, const float* __restrict__ rel_w,
    float* __restrict__ out) {
  __shared__ unsigned short k_lds[4][208 * 16];  // [head][key][d]
  __shared__ unsigned short v_lds[4][16 * 224];  // [head][d][key-slot perm]

  const int tid = threadIdx.x;
  const int win = blockIdx.x;
  const int b = win / (NH * NW);
  const int wrem = win - b * (NH * NW);
  const int bh = wrem / NW;
  const int bw = wrem - bh * NW;
  const int y0 = bh * BLK - HALO;
  const int x0 = bw * BLK - HALO;

  // ---- stage K (+rel, ->bf16) rows and V^T (permuted cols) for all heads ---
  for (int i = tid; i < 224 * 16; i += 256) {   // 14 iters exactly
    const int pixel = i >> 4;                   // 0..223 (196..223 virtual)
    const int g = i & 15;                       // 8 k-chunks, 8 v-chunks
    const int wy = pixel / WIN;                 // 0..15
    const int wx = pixel - wy * WIN;
    const int y = y0 + wy, xx = x0 + wx;
    const bool inb = (y >= 0) & (y < H) & (xx >= 0) & (xx < W);
    uint4 raw = make_uint4(0u, 0u, 0u, 0u);
    if (inb)
      raw = *reinterpret_cast<const uint4*>(
          qkv + ((size_t)(b * HW + y * W + xx)) * O + C + g * 8);
    const unsigned short* us = reinterpret_cast<const unsigned short*>(&raw);
    const int head = (g & 7) >> 1;
    const int c0 = (g & 1) * 8;
    if (g < 8) {  // K: unpack, +rel, repack bf16
      const int wyc = (wy < WIN) ? wy : (WIN - 1);  // clamp for virtual rows
      const float* relp = (g & 1) ? (rel_w + wx * 8) : (rel_h + wyc * 8);
      const float4 r0 = *reinterpret_cast<const float4*>(relp);
      const float4 r1 = *reinterpret_cast<const float4*>(relp + 4);
      float rl[8] = {r0.x, r0.y, r0.z, r0.w, r1.x, r1.y, r1.z, r1.w};
      unsigned short res[8];
#pragma unroll
      for (int e = 0; e < 8; ++e) res[e] = f2bf(bf2f(us[e]) + rl[e]);
      if (pixel < 208) {
        uint4 packed;
        unsigned int* pw = reinterpret_cast<unsigned int*>(&packed);
#pragma unroll
        for (int e = 0; e < 4; ++e)
          pw[e] = (unsigned int)res[2 * e] | ((unsigned int)res[2 * e + 1] << 16);
        *reinterpret_cast<uint4*>(&k_lds[head][pixel * 16 + c0]) = packed;
      }
    } else {  // V: transposed store into PV slot order
      const int r32 = pixel & 31;
      const int j = (((r32 >> 2) & 3) << 3) | ((r32 >> 4) << 2) | (r32 & 3);
      const int col = (pixel & ~31) | j;
#pragma unroll
      for (int e = 0; e < 8; ++e) v_lds[head][(c0 + e) * 224 + col] = us[e];
    }
  }
  __syncthreads();

  const int lane = tid & 63;
  const int head = tid >> 6;
  const int r = lane & 15;   // qrow offset / V^T channel
  const int hq = lane >> 4;  // 16-lane group
  const unsigned short* kbase = k_lds[head];
  const unsigned short* vbase = v_lds[head];
  const short8v z8 = {0, 0, 0, 0, 0, 0, 0, 0};

  for (int qs = 0; qs < 4; ++qs) {
    const int qrow = qs * 16 + r;
    const int y = bh * BLK + (qrow >> 3);
    const int xx = bw * BLK + (qrow & 7);

    // Q^T fragment direct from global: Q[qrow][8h..8h+7], h>=2 -> zero pad
    short8v qf = *reinterpret_cast<const short8v*>(
        qkv + ((size_t)(b * HW + y * W + xx)) * O + head * D + (hq & 1) * 8);
    qf = (hq < 2) ? qf : z8;

    // sim^T tiles: D col=lane&15=qrow, row=4*hq+reg=key-in-tile
    f32x4 sim[13];
#pragma unroll
    for (int t = 0; t < 13; ++t) {
      short8v kf = *reinterpret_cast<const short8v*>(
          kbase + (16 * t + r) * 16 + (hq & 1) * 8);
      kf = (hq < 2) ? kf : z8;
      f32x4 z4 = {0.f, 0.f, 0.f, 0.f};
      sim[t] = mfma_bf16(kf, qf, z4);
    }

    // softmax over keys (regs x tiles, then lanes ^16, ^32)
    float m = -1e30f;
#pragma unroll
    for (int t = 0; t < 13; ++t)
#pragma unroll
      for (int e = 0; e < 4; ++e) m = fmaxf(m, sim[t][e]);
    m = fmaxf(m, __shfl_xor(m, 16));
    m = fmaxf(m, __shfl_xor(m, 32));
    float sum = 0.f;
#pragma unroll
    for (int t = 0; t < 13; ++t) {
#pragma unroll
      for (int e = 0; e < 4; ++e) {
        float p = __expf(sim[t][e] - m);
        if (t == 12 && hq >= 1) p = 0.f;  // key >= 196: pad
        sim[t][e] = p;
        sum += p;
      }
    }
    sum += __shfl_xor(sum, 16);
    sum += __shfl_xor(sum, 32);
    const float inv = 1.f / sum;

    // PV: O^T = sum_tau mfma(V^T frag, P^T frag)
    f32x4 oacc = {0.f, 0.f, 0.f, 0.f};
#pragma unroll
    for (int tau = 0; tau < 7; ++tau) {
      short8v pf;
#pragma unroll
      for (int e = 0; e < 4; ++e) pf[e] = (short)f2bf(sim[2 * tau][e]);
#pragma unroll
      for (int e = 0; e < 4; ++e)
        pf[4 + e] = (2 * tau + 1 < 13) ? (short)f2bf(sim[2 * tau + 1][e]) : (short)0;
      short8v vf = *reinterpret_cast<const short8v*>(
          vbase + r * 224 + 32 * tau + 8 * hq);
      oacc = mfma_bf16(vf, pf, oacc);
    }

    // epilogue: lane holds O^T[c=4*hq+e][qrow]; scale by 1/sum
    float* op = out + ((size_t)b * C + head * D + 4 * hq) * HW + y * W + xx;
#pragma unroll
    for (int e = 0; e < 4; ++e) op[(size_t)e * HW] = oacc[e] * inv;
  }
}

extern "C" void kernel_launch(void* const* d_in, const int* in_sizes, int n_in,
                              void* d_out, int out_size, void* d_ws,
                              size_t ws_size, hipStream_t stream) {
  const float* x = (const float*)d_in[0];      // (4, 64, 192, 192)
  const float* w_qkv = (const float*)d_in[1];  // (192, 64)
  const float* rel_h = (const float*)d_in[2];  // (1, 14, 1, 8)
  const float* rel_w = (const float*)d_in[3];  // (1, 1, 14, 8)
  float* out = (float*)d_out;                  // (4, 64, 192, 192)

  unsigned short* qkv = (unsigned short*)d_ws;  // (B, H, W, O) bf16

  qkv_mfma<<<B * HW / 128, 256, 0, stream>>>(x, w_qkv, qkv);
  attn_kernel<<<B * NH * NW, 256, 0, stream>>>(qkv, rel_h, rel_w, out);
}

// Round 4
// 79.782 us; speedup vs baseline: 4.5264x; 1.4854x over previous
//
#include <hip/hip_runtime.h>
#include <hip/hip_bf16.h>

// Problem constants
constexpr int B = 4, C = 64, H = 192, W = 192;
constexpr int HEADS = 4, D = 16;           // d = C/HEADS
constexpr int BLK = 8, HALO = 3, WIN = 14; // WIN = BLK + 2*HALO
constexpr int NH = H / BLK, NW = W / BLK;  // 24 x 24 windows
constexpr int HW = H * W;                  // 36864
constexpr int O = 3 * C;                   // 192 qkv channels
constexpr int KHEAD = 208 * 16 + 8;        // K plane: 208 rows x 16d, +8 pad (bank shift)
constexpr int VHEAD = 232 * 16 + 8;        // V^T plane: 16 d-rows x 232 slots, +8 pad

typedef __attribute__((ext_vector_type(8))) short short8v;
typedef __attribute__((ext_vector_type(8))) __bf16 bf16x8;
typedef __attribute__((ext_vector_type(4))) float f32x4;

__device__ inline f32x4 mfma_bf16(short8v a, short8v b, f32x4 c) {
  return __builtin_amdgcn_mfma_f32_16x16x32_bf16(
      __builtin_bit_cast(bf16x8, a), __builtin_bit_cast(bf16x8, b), c, 0, 0, 0);
}

__device__ inline float bf2f(unsigned short u) {
  union { unsigned int i; float f; } v;
  v.i = ((unsigned int)u) << 16;
  return v.f;
}
__device__ inline unsigned short f2bf(float f) {
  __bf16 h = (__bf16)f;
  return __builtin_bit_cast(unsigned short, h);
}

// ---------------------------------------------------------------------------
// Kernel 1: qkv projection as MFMA GEMM (unchanged from R3 — ~18us, near HBM
// floor). D^T = W * X^T per 16x16 tile; output (B,H,W,O) bf16 pixel-major.
// ---------------------------------------------------------------------------
__global__ __launch_bounds__(256) void qkv_mfma(
    const float* __restrict__ x, const float* __restrict__ w,
    unsigned short* __restrict__ qkv) {
  __shared__ unsigned short wlds[192 * 64];
  const int tid = threadIdx.x;

  const float4* wf4 = reinterpret_cast<const float4*>(w);
#pragma unroll
  for (int it = 0; it < 12; ++it) {
    const int idx = it * 256 + tid;  // 3072 float4s
    const int o = idx >> 4;
    const int c = (idx & 15) << 2;
    const float4 wv = wf4[idx];
    ushort4 st;
    st.x = f2bf(wv.x);
    st.y = f2bf(wv.y);
    st.z = f2bf(wv.z);
    st.w = f2bf(wv.w);
    const int sw = (((c >> 3) ^ (o & 7)) << 3) + (c & 4);
    *reinterpret_cast<ushort4*>(&wlds[o * 64 + sw]) = st;
  }

  const int wave = tid >> 6, lane = tid & 63;
  const int p = lane & 15, g = lane >> 4;
  const int pix_w = blockIdx.x * 128 + wave * 32;
  const int b = pix_w / HW;
  const int hw = pix_w - b * HW + p;
  const float* xb = x + (size_t)b * C * HW;

  short8v xf[2][2];
#pragma unroll
  for (int pt = 0; pt < 2; ++pt) {
#pragma unroll
    for (int ks = 0; ks < 2; ++ks) {
      unsigned short u[8];
#pragma unroll
      for (int j = 0; j < 8; ++j)
        u[j] = f2bf(xb[(size_t)(ks * 32 + g * 8 + j) * HW + hw + pt * 16]);
      unsigned int pw[4];
#pragma unroll
      for (int e = 0; e < 4; ++e)
        pw[e] = (unsigned int)u[2 * e] | ((unsigned int)u[2 * e + 1] << 16);
      xf[pt][ks] = __builtin_bit_cast(short8v, *reinterpret_cast<uint4*>(pw));
    }
  }
  __syncthreads();

#pragma unroll
  for (int ot = 0; ot < 12; ++ot) {
    short8v af[2];
#pragma unroll
    for (int ks = 0; ks < 2; ++ks)
      af[ks] = *reinterpret_cast<const short8v*>(
          wlds + (ot * 16 + p) * 64 + (((((ks << 2) | g)) ^ (p & 7)) << 3));
    const float s = (ot < 4) ? 0.25f : 1.0f;
#pragma unroll
    for (int pt = 0; pt < 2; ++pt) {
      f32x4 acc = {0.f, 0.f, 0.f, 0.f};
      acc = mfma_bf16(af[0], xf[pt][0], acc);
      acc = mfma_bf16(af[1], xf[pt][1], acc);
      ushort4 st;
      st.x = f2bf(acc[0] * s);
      st.y = f2bf(acc[1] * s);
      st.z = f2bf(acc[2] * s);
      st.w = f2bf(acc[3] * s);
      *reinterpret_cast<ushort4*>(
          qkv + (size_t)(pix_w + pt * 16 + p) * O + ot * 16 + g * 4) = st;
    }
  }
}

// ---------------------------------------------------------------------------
// Kernel 2: MFMA window attention v2.
// 512 threads = 8 waves per window; wave = (head, q-half), 2 q-subtiles each.
// Staging wave-specialized: waves 0-3 stage K (+rel), waves 4-7 stage V^T.
// All staging global loads issued before any LDS write (latency overlap).
// K: chunk-XOR swizzle + head pad -> ~2-way max on ds_read_b128/write.
// V^T: rows padded to 232 (+head pad) -> 2-way reads, spread writes.
// XCD-aware block swizzle: 2304 windows = 8 * 288 contiguous stripes.
// ---------------------------------------------------------------------------
__global__ __launch_bounds__(512, 4) void attn_kernel(
    const unsigned short* __restrict__ qkv,
    const float* __restrict__ rel_h, const float* __restrict__ rel_w,
    float* __restrict__ out) {
  __shared__ unsigned short k_lds[4 * KHEAD];
  __shared__ unsigned short v_lds[4 * VHEAD];

  const int tid = threadIdx.x;
  const int blk = blockIdx.x;
  const int win = (blk & 7) * 288 + (blk >> 3);  // bijective: 2304 % 8 == 0
  const int b = win / (NH * NW);
  const int wrem = win - b * (NH * NW);
  const int bh = wrem / NW;
  const int bw = wrem - bh * NW;
  const int y0 = bh * BLK - HALO;
  const int x0 = bw * BLK - HALO;

  // ---- staging phase 1: issue all global loads (7 per thread, in flight) --
  const int sthd = tid & 255;     // index within K- or V-half of the block
  const bool isK = tid < 256;
  const int secbase = isK ? C : 2 * C;
  uint4 raw[7];
#pragma unroll
  for (int it = 0; it < 7; ++it) {
    const int item = sthd + it * 256;  // 0..1791
    const int pixel = item >> 3;       // 0..223
    const int g = item & 7;            // head*2 + c-chunk
    const int wy = pixel / WIN;
    const int wx = pixel - wy * WIN;
    const int y = y0 + wy, xx = x0 + wx;
    const bool inb = (y >= 0) & (y < H) & (xx >= 0) & (xx < W);
    uint4 rv = make_uint4(0u, 0u, 0u, 0u);
    if (inb)
      rv = *reinterpret_cast<const uint4*>(
          qkv + ((size_t)(b * HW + y * W + xx)) * O + secbase + g * 8);
    raw[it] = rv;
  }

  // ---- prefetch Q fragments for this wave's two q-subtiles ----
  const int lane = tid & 63;
  const int wv = tid >> 6;   // 0..7
  const int head = wv & 3;
  const int qhalf = wv >> 2; // 0..1
  const int r = lane & 15, hq = lane >> 4;
  const short8v z8 = {0, 0, 0, 0, 0, 0, 0, 0};
  short8v qf[2];
#pragma unroll
  for (int q2 = 0; q2 < 2; ++q2) {
    const int qrow = (qhalf * 2 + q2) * 16 + r;
    const int y = bh * BLK + (qrow >> 3);
    const int xx = bw * BLK + (qrow & 7);
    short8v t = *reinterpret_cast<const short8v*>(
        qkv + ((size_t)(b * HW + y * W + xx)) * O + head * D + (hq & 1) * 8);
    qf[q2] = (hq < 2) ? t : z8;
  }

  // ---- staging phase 2: process + LDS writes (wave-uniform branch) ----
  if (isK) {
#pragma unroll
    for (int it = 0; it < 7; ++it) {
      const int item = sthd + it * 256;
      const int pixel = item >> 3;
      const int g = item & 7;
      const int wy = pixel / WIN;
      const int wx = pixel - wy * WIN;
      const unsigned short* us = reinterpret_cast<const unsigned short*>(&raw[it]);
      const int hd = g >> 1;
      const int wyc = (wy < WIN) ? wy : (WIN - 1);
      const float* relp = (g & 1) ? (rel_w + wx * 8) : (rel_h + wyc * 8);
      const float4 r0 = *reinterpret_cast<const float4*>(relp);
      const float4 r1 = *reinterpret_cast<const float4*>(relp + 4);
      const float rl[8] = {r0.x, r0.y, r0.z, r0.w, r1.x, r1.y, r1.z, r1.w};
      unsigned short res[8];
#pragma unroll
      for (int e = 0; e < 8; ++e) res[e] = f2bf(bf2f(us[e]) + rl[e]);
      if (pixel < 208) {
        uint4 packed;
        unsigned int* pw = reinterpret_cast<unsigned int*>(&packed);
#pragma unroll
        for (int e = 0; e < 4; ++e)
          pw[e] = (unsigned int)res[2 * e] | ((unsigned int)res[2 * e + 1] << 16);
        const int cw = (g & 1) ^ ((pixel >> 2) & 1);  // chunk-XOR swizzle
        *reinterpret_cast<uint4*>(
            &k_lds[hd * KHEAD + pixel * 16 + (cw << 3)]) = packed;
      }
    }
  } else {
#pragma unroll
    for (int it = 0; it < 7; ++it) {
      const int item = sthd + it * 256;
      const int pixel = item >> 3;
      const int g = item & 7;
      const unsigned short* us = reinterpret_cast<const unsigned short*>(&raw[it]);
      const int hd = g >> 1;
      const int c0 = (g & 1) * 8;
      const int r32 = pixel & 31;  // PV slot permutation
      const int j = (((r32 >> 2) & 3) << 3) | ((r32 >> 4) << 2) | (r32 & 3);
      const int col = (pixel & ~31) | j;
      unsigned short* vp = &v_lds[hd * VHEAD + c0 * 232 + col];
#pragma unroll
      for (int e = 0; e < 8; ++e) vp[e * 232] = us[e];
    }
  }
  __syncthreads();

  const unsigned short* kbase = k_lds + head * KHEAD;
  const unsigned short* vbase = v_lds + head * VHEAD;
  const int kchunk = (((hq & 1) ^ ((r >> 2) & 1)) << 3);  // read-side swizzle

  for (int q2 = 0; q2 < 2; ++q2) {
    const int qrow = (qhalf * 2 + q2) * 16 + r;
    const int y = bh * BLK + (qrow >> 3);
    const int xx = bw * BLK + (qrow & 7);

    // sim^T tiles: D col=lane&15=qrow, row=4*hq+e = key-in-tile
    f32x4 sim[13];
#pragma unroll
    for (int t = 0; t < 13; ++t) {
      short8v kf = *reinterpret_cast<const short8v*>(
          kbase + (16 * t + r) * 16 + kchunk);
      kf = (hq < 2) ? kf : z8;
      f32x4 z4 = {0.f, 0.f, 0.f, 0.f};
      sim[t] = mfma_bf16(kf, qf[q2], z4);
    }

    // softmax over keys (regs x tiles, then lanes ^16, ^32)
    float m = -1e30f;
#pragma unroll
    for (int t = 0; t < 13; ++t)
#pragma unroll
      for (int e = 0; e < 4; ++e) m = fmaxf(m, sim[t][e]);
    m = fmaxf(m, __shfl_xor(m, 16));
    m = fmaxf(m, __shfl_xor(m, 32));
    float sum = 0.f;
#pragma unroll
    for (int t = 0; t < 13; ++t) {
#pragma unroll
      for (int e = 0; e < 4; ++e) {
        float p = __expf(sim[t][e] - m);
        if (t == 12 && hq >= 1) p = 0.f;  // keys >= 196: pad
        sim[t][e] = p;
        sum += p;
      }
    }
    sum += __shfl_xor(sum, 16);
    sum += __shfl_xor(sum, 32);
    const float inv = 1.f / sum;

    // PV: O^T = sum_tau mfma(V^T frag, P^T frag)
    f32x4 oacc = {0.f, 0.f, 0.f, 0.f};
#pragma unroll
    for (int tau = 0; tau < 7; ++tau) {
      short8v pf;
#pragma unroll
      for (int e = 0; e < 4; ++e) pf[e] = (short)f2bf(sim[2 * tau][e]);
#pragma unroll
      for (int e = 0; e < 4; ++e)
        pf[4 + e] = (2 * tau + 1 < 13) ? (short)f2bf(sim[2 * tau + 1][e]) : (short)0;
      short8v vfr = *reinterpret_cast<const short8v*>(
          vbase + r * 232 + 32 * tau + 8 * hq);
      oacc = mfma_bf16(vfr, pf, oacc);
    }

    // epilogue: lane holds O^T[c=4*hq+e][qrow]; scale by 1/sum
    float* op = out + ((size_t)b * C + head * D + 4 * hq) * HW + y * W + xx;
#pragma unroll
    for (int e = 0; e < 4; ++e) op[(size_t)e * HW] = oacc[e] * inv;
  }
}

extern "C" void kernel_launch(void* const* d_in, const int* in_sizes, int n_in,
                              void* d_out, int out_size, void* d_ws,
                              size_t ws_size, hipStream_t stream) {
  const float* x = (const float*)d_in[0];      // (4, 64, 192, 192)
  const float* w_qkv = (const float*)d_in[1];  // (192, 64)
  const float* rel_h = (const float*)d_in[2];  // (1, 14, 1, 8)
  const float* rel_w = (const float*)d_in[3];  // (1, 1, 14, 8)
  float* out = (float*)d_out;                  // (4, 64, 192, 192)

  unsigned short* qkv = (unsigned short*)d_ws;  // (B, H, W, O) bf16

  qkv_mfma<<<B * HW / 128, 256, 0, stream>>>(x, w_qkv, qkv);
  attn_kernel<<<B * NH * NW, 512, 0, stream>>>(qkv, rel_h, rel_w, out);
}

// Round 6
// 77.220 us; speedup vs baseline: 4.6766x; 1.0332x over previous
//
#include <hip/hip_runtime.h>
#include <hip/hip_bf16.h>

// Problem constants
constexpr int B = 4, C = 64, H = 192, W = 192;
constexpr int HEADS = 4, D = 16;           // d = C/HEADS
constexpr int BLK = 8, HALO = 3, WIN = 14; // WIN = BLK + 2*HALO
constexpr int NH = H / BLK, NW = W / BLK;  // 24 x 24 windows
constexpr int HW = H * W;                  // 36864
constexpr int O = 3 * C;                   // 192 qkv channels

// attn LDS layout (units: shorts)
constexpr int K_OFF = 0;                     // K: [208 pixels][8 chunks x 8ch], chunk XOR-swizzled
constexpr int VPLANE = 208 * 16 + 16;        // V plane: [208][16] + 16 pad
constexpr int V_OFF = 208 * 64;              // 13312
constexpr int RH_OFF = V_OFF + 4 * VPLANE;   // rel_h bf16 [16][8] (rows >=14 clamped)
constexpr int RW_OFF = RH_OFF + 128;         // rel_w bf16 [16][8]
constexpr int LDS_TOT = RW_OFF + 128;        // 26944 shorts = 53888 B

typedef __attribute__((ext_vector_type(4))) short short4v;
typedef __attribute__((ext_vector_type(8))) short short8v;
typedef __attribute__((ext_vector_type(8))) __bf16 bf16x8;
typedef __attribute__((ext_vector_type(4))) float f32x4;

__device__ inline f32x4 mfma_bf16(short8v a, short8v b, f32x4 c) {
  return __builtin_amdgcn_mfma_f32_16x16x32_bf16(
      __builtin_bit_cast(bf16x8, a), __builtin_bit_cast(bf16x8, b), c, 0, 0, 0);
}

__device__ inline unsigned short f2bf(float f) {
  __bf16 h = (__bf16)f;
  return __builtin_bit_cast(unsigned short, h);
}

// ---------------------------------------------------------------------------
// Kernel 1: qkv projection as MFMA GEMM (unchanged; ~12-18us, near HBM floor).
// q rows pre-scaled by d^-0.5 * log2(e) so attention works in exp2 domain.
// ---------------------------------------------------------------------------
__global__ __launch_bounds__(256) void qkv_mfma(
    const float* __restrict__ x, const float* __restrict__ w,
    unsigned short* __restrict__ qkv) {
  __shared__ unsigned short wlds[192 * 64];
  const int tid = threadIdx.x;

  const float4* wf4 = reinterpret_cast<const float4*>(w);
#pragma unroll
  for (int it = 0; it < 12; ++it) {
    const int idx = it * 256 + tid;  // 3072 float4s
    const int o = idx >> 4;
    const int c = (idx & 15) << 2;
    const float4 wv = wf4[idx];
    ushort4 st;
    st.x = f2bf(wv.x);
    st.y = f2bf(wv.y);
    st.z = f2bf(wv.z);
    st.w = f2bf(wv.w);
    const int sw = (((c >> 3) ^ (o & 7)) << 3) + (c & 4);
    *reinterpret_cast<ushort4*>(&wlds[o * 64 + sw]) = st;
  }

  const int wave = tid >> 6, lane = tid & 63;
  const int p = lane & 15, g = lane >> 4;
  const int pix_w = blockIdx.x * 128 + wave * 32;
  const int b = pix_w / HW;
  const int hw = pix_w - b * HW + p;
  const float* xb = x + (size_t)b * C * HW;

  short8v xf[2][2];
#pragma unroll
  for (int pt = 0; pt < 2; ++pt) {
#pragma unroll
    for (int ks = 0; ks < 2; ++ks) {
      unsigned short u[8];
#pragma unroll
      for (int j = 0; j < 8; ++j)
        u[j] = f2bf(xb[(size_t)(ks * 32 + g * 8 + j) * HW + hw + pt * 16]);
      unsigned int pw[4];
#pragma unroll
      for (int e = 0; e < 4; ++e)
        pw[e] = (unsigned int)u[2 * e] | ((unsigned int)u[2 * e + 1] << 16);
      xf[pt][ks] = __builtin_bit_cast(short8v, *reinterpret_cast<uint4*>(pw));
    }
  }
  __syncthreads();

#pragma unroll
  for (int ot = 0; ot < 12; ++ot) {
    short8v af[2];
#pragma unroll
    for (int ks = 0; ks < 2; ++ks)
      af[ks] = *reinterpret_cast<const short8v*>(
          wlds + (ot * 16 + p) * 64 + (((((ks << 2) | g)) ^ (p & 7)) << 3));
    // q pre-scale: d^-0.5 * log2(e) -> attention uses exp2 directly
    const float s = (ot < 4) ? 0.25f * 1.44269504f : 1.0f;
#pragma unroll
    for (int pt = 0; pt < 2; ++pt) {
      f32x4 acc = {0.f, 0.f, 0.f, 0.f};
      acc = mfma_bf16(af[0], xf[pt][0], acc);
      acc = mfma_bf16(af[1], xf[pt][1], acc);
      ushort4 st;
      st.x = f2bf(acc[0] * s);
      st.y = f2bf(acc[1] * s);
      st.z = f2bf(acc[2] * s);
      st.w = f2bf(acc[3] * s);
      *reinterpret_cast<ushort4*>(
          qkv + (size_t)(pix_w + pt * 16 + p) * O + ot * 16 + g * 4) = st;
    }
  }
}

// ---------------------------------------------------------------------------
// Kernel 2: MFMA window attention v3b.
// - rel folded into MFMA spare depth (A depth 16-23 = rel_h[wy], 24-31 =
//   rel_w[wx]; B depth 16-23 = q[0:8], 24-31 = q[8:16]) -> sim = q*(k+rel)
//   entirely in the matrix pipe; K/V staging = pure uint4 copies.
// - V stored linear [pixel][16] per head; V^T fragments via ds_read_b64_tr_b16
//   with PER-LANE address base + 8*lane (R5 bug: uniform addr broadcasts).
// - softmax in exp2 domain.
// ---------------------------------------------------------------------------
__global__ __launch_bounds__(512, 4) void attn_kernel(
    const unsigned short* __restrict__ qkv,
    const float* __restrict__ rel_h, const float* __restrict__ rel_w,
    float* __restrict__ out) {
  __shared__ __align__(16) unsigned short lds[LDS_TOT];

  const int tid = threadIdx.x;
  const int blk = blockIdx.x;
  const int win = (blk & 7) * 288 + (blk >> 3);  // XCD swizzle (2304 % 8 == 0)
  const int b = win / (NH * NW);
  const int wrem = win - b * (NH * NW);
  const int bh = wrem / NW;
  const int bw = wrem - bh * NW;
  const int y0 = bh * BLK - HALO;
  const int x0 = bw * BLK - HALO;

  // ---- rel tables -> bf16 LDS (rows >= 14 clamped to 13) ----
  if (tid < 256) {
    const int i = tid & 127;
    const int rr = i >> 3, cc = i & 7;
    const int rc = (rr < WIN) ? rr : (WIN - 1);
    const float* src = (tid < 128) ? rel_h : rel_w;
    lds[((tid < 128) ? RH_OFF : RW_OFF) + i] = f2bf(src[rc * 8 + cc]);
  }

  // ---- staging phase 1: issue all K/V global loads (T14 split) ----
  // items 0..1663 = K (pixel 0..207, 8 chunks), 1664..3327 = V
  uint4 raw[7];
#pragma unroll
  for (int it = 0; it < 7; ++it) {
    const int item = tid + it * 512;
    const bool isK = item < 1664;
    const int li = isK ? item : item - 1664;
    const int pixel = li >> 3;
    const int g = li & 7;
    const int wy = pixel / WIN;  // up to 14 for pad pixels
    const int wx = pixel - wy * WIN;
    const int y = y0 + wy, xx = x0 + wx;
    const bool inb =
        (item < 3328) & (y >= 0) & (y < H) & (xx >= 0) & (xx < W);
    uint4 rv = make_uint4(0u, 0u, 0u, 0u);
    if (inb)
      rv = *reinterpret_cast<const uint4*>(
          qkv + ((size_t)(b * HW + y * W + xx)) * O + (isK ? C : 2 * C) + g * 8);
    raw[it] = rv;
  }

  // ---- Q fragment prefetch (hq>=2 lanes supply q[0:8]/q[8:16] against the
  //      rel depth slots — no zero select anywhere) ----
  const int lane = tid & 63;
  const int wv = tid >> 6;
  const int head = wv & 3;
  const int qhalf = wv >> 2;
  const int r = lane & 15, hq = lane >> 4;
  short8v qf[2];
#pragma unroll
  for (int q2 = 0; q2 < 2; ++q2) {
    const int qrow = (qhalf * 2 + q2) * 16 + r;
    const int y = bh * BLK + (qrow >> 3);
    const int xx = bw * BLK + (qrow & 7);
    qf[q2] = *reinterpret_cast<const short8v*>(
        qkv + ((size_t)(b * HW + y * W + xx)) * O + head * D + (hq & 1) * 8);
  }

  // ---- staging phase 2: LDS writes (pure copies) ----
#pragma unroll
  for (int it = 0; it < 7; ++it) {
    const int item = tid + it * 512;
    if (item < 3328) {
      const bool isK = item < 1664;
      const int li = isK ? item : item - 1664;
      const int pixel = li >> 3;
      const int g = li & 7;
      if (isK) {
        const int ch = (g ^ pixel) & 7;  // chunk XOR swizzle
        *reinterpret_cast<uint4*>(&lds[K_OFF + pixel * 64 + ch * 8]) = raw[it];
      } else {
        const int hd = g >> 1, c8 = g & 1;
        *reinterpret_cast<uint4*>(
            &lds[V_OFF + hd * VPLANE + pixel * 16 + c8 * 8]) = raw[it];
      }
    }
  }
  __syncthreads();

  // ---- per-lane A-frag LDS offsets (shorts), one per QK tile ----
  // hq<2: K row chunks; hq==2: rel_h[wy]; hq==3: rel_w[wx]
  int koff[13];
#pragma unroll
  for (int t = 0; t < 13; ++t) {
    const int row = 16 * t + r;
    const int wy = row / WIN;
    const int wx = row - wy * WIN;
    const int a_k =
        K_OFF + row * 64 + ((((head << 1) | (hq & 1)) ^ (row & 7)) << 3);
    const int a_rh = RH_OFF + wy * 8;
    const int a_rw = RW_OFF + wx * 8;
    koff[t] = (hq < 2) ? a_k : ((hq == 2) ? a_rh : a_rw);
  }

  // ---- V^T fragments via hardware transpose-read, PER-LANE addresses:
  //      lane l supplies base + 8*l; net effect (m162): lane(r,hq) elem j =
  //      V[32*tau + 4*hq + j][r]; offset:512 gives +16 pixels. ----
  const unsigned vbase_addr =
      (unsigned)(unsigned long long)(const void*)&lds[V_OFF + head * VPLANE] +
      (unsigned)(lane * 8);
  short4v vlo[7], vhi[7];
#pragma unroll
  for (int tau = 0; tau < 7; ++tau) {
    const unsigned va = vbase_addr + tau * 1024;
    asm volatile("ds_read_b64_tr_b16 %0, %1" : "=v"(vlo[tau]) : "v"(va));
    if (tau < 6) {
      asm volatile("ds_read_b64_tr_b16 %0, %1 offset:512"
                   : "=v"(vhi[tau])
                   : "v"(va));
    } else {
      vhi[tau] = (short4v){0, 0, 0, 0};  // slots 208-223: pf is 0 anyway
    }
  }

  for (int q2 = 0; q2 < 2; ++q2) {
    // ---- sim^T tiles: augmented MFMA does q*(k+rel) in one op ----
    f32x4 sim[13];
#pragma unroll
    for (int t = 0; t < 13; ++t) {
      const short8v kf = *reinterpret_cast<const short8v*>(&lds[koff[t]]);
      f32x4 z4 = {0.f, 0.f, 0.f, 0.f};
      sim[t] = mfma_bf16(kf, qf[q2], z4);
    }

    // ---- softmax over keys (exp2 domain) ----
    float m = -1e30f;
#pragma unroll
    for (int t = 0; t < 13; ++t)
#pragma unroll
      for (int e = 0; e < 4; ++e) m = fmaxf(m, sim[t][e]);
    m = fmaxf(m, __shfl_xor(m, 16));
    m = fmaxf(m, __shfl_xor(m, 32));
    float sum = 0.f;
#pragma unroll
    for (int t = 0; t < 13; ++t) {
#pragma unroll
      for (int e = 0; e < 4; ++e) {
        float p = exp2f(sim[t][e] - m);
        if (t == 12 && hq >= 1) p = 0.f;  // keys >= 196: pad
        sim[t][e] = p;
        sum += p;
      }
    }
    sum += __shfl_xor(sum, 16);
    sum += __shfl_xor(sum, 32);
    const float inv = 1.f / sum;

    // ensure all tr-reads landed before PV consumes vf (rule #18)
    asm volatile("s_waitcnt lgkmcnt(0)" ::: "memory");
    __builtin_amdgcn_sched_barrier(0);

    // ---- PV: O^T = sum_tau mfma(V^T frag, P^T frag) ----
    f32x4 oacc = {0.f, 0.f, 0.f, 0.f};
#pragma unroll
    for (int tau = 0; tau < 7; ++tau) {
      short8v pf;
#pragma unroll
      for (int e = 0; e < 4; ++e) pf[e] = (short)f2bf(sim[2 * tau][e]);
#pragma unroll
      for (int e = 0; e < 4; ++e)
        pf[4 + e] =
            (2 * tau + 1 < 13) ? (short)f2bf(sim[2 * tau + 1][e]) : (short)0;
      const short8v vf = __builtin_shufflevector(vlo[tau], vhi[tau], 0, 1, 2,
                                                 3, 4, 5, 6, 7);
      oacc = mfma_bf16(vf, pf, oacc);
    }

    // ---- epilogue: lane holds O^T[c=4*hq+e][qrow]; scale by 1/sum ----
    const int qrow = (qhalf * 2 + q2) * 16 + r;
    const int y = bh * BLK + (qrow >> 3);
    const int xx = bw * BLK + (qrow & 7);
    float* op = out + ((size_t)b * C + head * D + 4 * hq) * HW + y * W + xx;
#pragma unroll
    for (int e = 0; e < 4; ++e) op[(size_t)e * HW] = oacc[e] * inv;
  }
}

extern "C" void kernel_launch(void* const* d_in, const int* in_sizes, int n_in,
                              void* d_out, int out_size, void* d_ws,
                              size_t ws_size, hipStream_t stream) {
  const float* x = (const float*)d_in[0];      // (4, 64, 192, 192)
  const float* w_qkv = (const float*)d_in[1];  // (192, 64)
  const float* rel_h = (const float*)d_in[2];  // (1, 14, 1, 8)
  const float* rel_w = (const float*)d_in[3];  // (1, 1, 14, 8)
  float* out = (float*)d_out;                  // (4, 64, 192, 192)

  unsigned short* qkv = (unsigned short*)d_ws;  // (B, H, W, O) bf16

  qkv_mfma<<<B * HW / 128, 256, 0, stream>>>(x, w_qkv, qkv);
  attn_kernel<<<B * NH * NW, 512, 0, stream>>>(qkv, rel_h, rel_w, out);
}